// Round 1
// baseline (239.852 us; speedup 1.0000x reference)
//
#include <hip/hip_runtime.h>
#include <hip/hip_bf16.h>

#define N_EDGES 1000000
#define HID 128
#define VOC 105
#define TROW 136   // padded T/U row length in fp16 elems (272 B, breaks 256B bank alignment)

// ws layout in fp16 elements
#define WSU_T   0                         // [105][136]
#define WSU_U   (VOC * TROW)              // 14280
#define WSU_W3  (2 * VOC * TROW)          // 28560 : [4 ks][8 nf][64 lane][8] = 16384
#define WSU_WP  (WSU_W3 + 16384)          // 44944 : [8 nf][64 lane][8] = 4096
#define WSU_TUW (WSU_W3 + 16384)          // T+U+W3 contiguous span = 44944 elems
#define WSU_END (WSU_WP + 4096)           // 49040 elems = 98080 B

typedef float  f32x4 __attribute__((ext_vector_type(4)));
typedef _Float16 f16x8 __attribute__((ext_vector_type(8)));

// ---------------- prep: build T/U tables + pre-packed MFMA fragments ----------------
__global__ void prep_kernel(const float* __restrict__ emb_table,
                            const float* __restrict__ W_pair,
                            const float* __restrict__ W_emb,
                            _Float16* __restrict__ ws) {
    int b = blockIdx.x, t = threadIdx.x;
    if (b < VOC) {
        // T[v] = emb[v] @ W_emb[0:128] ; U[v] = emb[v] @ W_emb[128:256]
        int v = b, which = t >> 7, h = t & 127;
        const float* wrows = W_emb + which * HID * HID;
        const float* ev = emb_table + v * HID;
        float acc = 0.f;
        for (int d = 0; d < HID; ++d) acc = fmaf(ev[d], wrows[d * HID + h], acc);
        ws[(which ? WSU_U : WSU_T) + v * TROW + h] = (_Float16)acc;
    } else if (b < VOC + 64) {
        // W3 = W_emb[256:384] packed as B-fragments for mfma_f32_16x16x32:
        // lane holds B[k=(lane>>4)*8+t][n=lane&15], tile (ks,nf)
        int idx = (b - VOC) * 256 + t;            // 0..16383
        int tt = idx & 7, lane = (idx >> 3) & 63, nf = (idx >> 9) & 7, ks = idx >> 12;
        int k = ks * 32 + (lane >> 4) * 8 + tt;
        int n = nf * 16 + (lane & 15);
        ws[WSU_W3 + idx] = (_Float16)W_emb[(2 * HID + k) * HID + n];
    } else {
        // W_pair packed as B-fragments, K padded 16->32 with zeros
        int idx = (b - VOC - 64) * 256 + t;       // 0..4095
        int tt = idx & 7, lane = (idx >> 3) & 63, nf = idx >> 9;
        int k = (lane >> 4) * 8 + tt;
        int n = nf * 16 + (lane & 15);
        float v = (k < 16) ? W_pair[k * HID + n] : 0.f;
        ws[WSU_WP + idx] = (_Float16)v;
    }
}

// ---------------- main: fused pb-GEMM + table-add + edge-GEMM + silu ----------------
__device__ __forceinline__ float silu_f(float x) {
    return x / (1.f + __expf(-x));
}

__global__ __launch_bounds__(512) void edge_kernel(
    const int*   __restrict__ xv,
    const float* __restrict__ pair_basis,
    const int*   __restrict__ ii,
    const int*   __restrict__ jj,
    const float* __restrict__ b_pair,
    const float* __restrict__ b_emb,
    const _Float16* __restrict__ ws,
    float* __restrict__ out)
{
    __shared__ __align__(16) _Float16 sTUW[WSU_TUW];   // T,U,W3 : 89888 B
    __shared__ __align__(16) _Float16 sPB[8][16 * HID]; // per-wave pb tiles: 32768 B

    const int tid = threadIdx.x;
    // stage T/U/W3 (contiguous in ws) into LDS, 16B chunks
    {
        const uint4* src = (const uint4*)ws;
        uint4* dst = (uint4*)sTUW;
        for (int c = tid; c < (WSU_TUW * 2 / 16); c += 512) dst[c] = src[c];
    }
    const int lane = tid & 63;
    const int w    = tid >> 6;     // wave 0..7
    const int m    = lane & 15;    // MFMA row/col-local index
    const int g    = lane >> 4;    // 0..3

    // resident W_pair B-fragments + bias registers
    f16x8 wpf[8];
    #pragma unroll
    for (int nf = 0; nf < 8; ++nf)
        wpf[nf] = *(const f16x8*)(ws + WSU_WP + (nf * 64 + lane) * 8);
    float bpr[8], ber[8];
    #pragma unroll
    for (int nf = 0; nf < 8; ++nf) {
        bpr[nf] = b_pair[m + 16 * nf];
        ber[nf] = b_emb[m + 16 * nf];
    }
    __syncthreads();

    const _Float16* sT  = sTUW;
    const _Float16* sU  = sTUW + WSU_U;
    const _Float16* sW3 = sTUW + WSU_W3;
    _Float16* myPB = &sPB[w][0];

    const int ntiles = (N_EDGES + 127) >> 7;   // 128 edges per block-tile (16/wave)
    for (int tile = blockIdx.x; tile < ntiles; tile += (int)gridDim.x) {
        const int e0 = tile * 128 + w * 16;
        if (e0 >= N_EDGES) continue;           // no barriers inside loop: safe

        // ---- A1: pair_basis[e0+m][0..15] as fp16, K padded to 32 (g>=2 -> 0) ----
        f16x8 a1 = {0, 0, 0, 0, 0, 0, 0, 0};
        if (g < 2) {
            const float* pr = pair_basis + (size_t)(e0 + m) * 16 + g * 8;
            f32x4 p0 = *(const f32x4*)pr;
            f32x4 p1 = *(const f32x4*)(pr + 4);
            a1[0] = (_Float16)p0[0]; a1[1] = (_Float16)p0[1];
            a1[2] = (_Float16)p0[2]; a1[3] = (_Float16)p0[3];
            a1[4] = (_Float16)p1[0]; a1[5] = (_Float16)p1[1];
            a1[6] = (_Float16)p1[2]; a1[7] = (_Float16)p1[3];
        }

        // ---- pb = silu(pair @ W_pair + b_pair), written transposed-to-A-layout in LDS ----
        const f32x4 zero = {0.f, 0.f, 0.f, 0.f};
        #pragma unroll
        for (int nf = 0; nf < 8; ++nf) {
            f32x4 c1 = __builtin_amdgcn_mfma_f32_16x16x32_f16(a1, wpf[nf], zero, 0, 0, 0);
            #pragma unroll
            for (int r = 0; r < 4; ++r) {
                float s = silu_f(c1[r] + bpr[nf]);
                int el = 4 * g + r;                       // edge-local row
                int boff = ((el * 256 + (m + 16 * nf) * 2) ^ ((el & 7) << 4));
                *(_Float16*)((char*)myPB + boff) = (_Float16)s;
            }
        }

        // ---- read back as A-fragments (ds_read_b128, same XOR swizzle) ----
        f16x8 a2[4];
        #pragma unroll
        for (int ks = 0; ks < 4; ++ks) {
            int boff = ((m * 256 + ks * 64 + g * 16) ^ ((m & 7) << 4));
            a2[ks] = *(const f16x8*)((const char*)myPB + boff);
        }

        // ---- C init: T[x[i]] + U[x[j]] + b_emb ----
        f32x4 acc[8];
        #pragma unroll
        for (int r = 0; r < 4; ++r) {
            int er = e0 + 4 * g + r;
            int vi = xv[ii[er]];
            int vj = xv[jj[er]];
            const _Float16* tr = sT + vi * TROW;
            const _Float16* ur = sU + vj * TROW;
            #pragma unroll
            for (int nf = 0; nf < 8; ++nf) {
                int h = m + 16 * nf;
                acc[nf][r] = (float)tr[h] + (float)ur[h] + ber[nf];
            }
        }

        // ---- main GEMM: acc += pb @ W3 ----
        #pragma unroll
        for (int nf = 0; nf < 8; ++nf) {
            #pragma unroll
            for (int ks = 0; ks < 4; ++ks) {
                f16x8 bf = *(const f16x8*)(sW3 + ((ks * 8 + nf) * 64 + lane) * 8);
                acc[nf] = __builtin_amdgcn_mfma_f32_16x16x32_f16(a2[ks], bf, acc[nf], 0, 0, 0);
            }
        }

        // ---- epilogue: silu + store ----
        #pragma unroll
        for (int nf = 0; nf < 8; ++nf) {
            #pragma unroll
            for (int r = 0; r < 4; ++r) {
                float s = silu_f(acc[nf][r]);
                out[(size_t)(e0 + 4 * g + r) * HID + m + 16 * nf] = s;
            }
        }
    }
}

extern "C" void kernel_launch(void* const* d_in, const int* in_sizes, int n_in,
                              void* d_out, int out_size, void* d_ws, size_t ws_size,
                              hipStream_t stream) {
    const int*   x          = (const int*)d_in[0];
    const float* pair_basis = (const float*)d_in[1];
    const int*   ii         = (const int*)d_in[2];
    const int*   jj         = (const int*)d_in[3];
    const float* emb_table  = (const float*)d_in[4];
    const float* W_pair     = (const float*)d_in[5];
    const float* b_pair     = (const float*)d_in[6];
    const float* W_emb      = (const float*)d_in[7];
    const float* b_emb      = (const float*)d_in[8];
    _Float16* ws = (_Float16*)d_ws;
    float* out = (float*)d_out;

    prep_kernel<<<VOC + 64 + 16, 256, 0, stream>>>(emb_table, W_pair, W_emb, ws);
    edge_kernel<<<512, 512, 0, stream>>>(x, pair_basis, ii, jj, b_pair, b_emb, ws, out);
}

// Round 2
// 205.586 us; speedup vs baseline: 1.1667x; 1.1667x over previous
//
#include <hip/hip_runtime.h>
#include <hip/hip_bf16.h>

#define N_EDGES 1000000
#define HID 128
#define VOC 105

// ws layout (fp16 element offsets)
#define WSU_T   0                     // [105][128] T = emb@W_emb[0:128] + b_emb  (logical cols)
#define WSU_U   (VOC * HID)           // 13440 : [105][128] U = emb@W_emb[128:256]
#define WSU_W3  (2 * VOC * HID)       // 26880 : W3 B-frags, 16384 elems
#define WSU_WP  (WSU_W3 + 16384)      // 43264 : W_pair A-frags (swapped gemm), 4096 elems
#define WSU_TUW (WSU_W3 + 16384)      // contiguous T+U+W3 span (elems) = 43264
#define WSB_VI  ((WSU_WP + 4096) * 2) // byte offset 94720 : u8 vi[N_EDGES]
#define WSB_VJ  (WSB_VI + N_EDGES)    // u8 vj[N_EDGES]

typedef float    f32x4 __attribute__((ext_vector_type(4)));
typedef _Float16 f16x8 __attribute__((ext_vector_type(8)));

// ---------------- prep: tables + pre-packed fragments + vocab pre-gather ----------------
__global__ void prep_kernel(const int*   __restrict__ xv,
                            const int*   __restrict__ ii,
                            const int*   __restrict__ jj,
                            const float* __restrict__ emb_table,
                            const float* __restrict__ W_pair,
                            const float* __restrict__ b_pair,
                            const float* __restrict__ W_emb,
                            const float* __restrict__ b_emb,
                            char* __restrict__ wsb) {
    _Float16* ws = (_Float16*)wsb;
    int b = blockIdx.x, t = threadIdx.x;
    if (b < VOC) {
        // T[v][h] = emb[v]@W_emb[0:128,h] + b_emb[h];  U[v][h] = emb[v]@W_emb[128:256,h]
        int v = b, which = t >> 7, h = t & 127;
        const float* wr = W_emb + which * HID * HID;
        const float* ev = emb_table + v * HID;
        float acc = which ? 0.f : b_emb[h];
        for (int d = 0; d < HID; ++d) acc = fmaf(ev[d], wr[d * HID + h], acc);
        ws[(which ? WSU_U : WSU_T) + v * HID + h] = (_Float16)acc;
    } else if (b < VOC + 64) {
        // W3 B-frags with K-permutation (matches swapped-pair-GEMM output) and
        // N-permutation h_out(nf,c)=8c+nf.  idx = q*512 + lane*8 + t, q = ks*8+nf
        int idx = (b - VOC) * 256 + t;            // 0..16383
        int tt = idx & 7, lane = (idx >> 3) & 63, q = idx >> 9;
        int ks = q >> 3, nf = q & 7;
        int hl = 16 * (tt >> 2) + 4 * (lane >> 4) + (tt & 3);   // logical k within 32-block
        int k = 32 * ks + hl;
        int n = 8 * (lane & 15) + nf;                            // permuted out col
        ws[WSU_W3 + idx] = (_Float16)W_emb[(2 * HID + k) * HID + n];
    } else if (b < VOC + 64 + 16) {
        // W_pair^T A-frags (A2[h][k] = W_pair[k][h]), bias b_pair folded at k==16
        int idx = (b - VOC - 64) * 256 + t;       // 0..4095
        int tt = idx & 7, lane = (idx >> 3) & 63, hf = idx >> 9;
        int k = 8 * (lane >> 4) + tt;
        int h = 16 * hf + (lane & 15);
        float v = (k < 16) ? W_pair[k * HID + h] : (k == 16 ? b_pair[h] : 0.f);
        ws[WSU_WP + idx] = (_Float16)v;
    } else {
        // vocab pre-gather: vi[e] = x[i[e]], vj[e] = x[j[e]] as bytes (VOC=105<256)
        int e4 = ((b - VOC - 64 - 16) * 256 + t) * 4;
        if (e4 < N_EDGES) {
            int4 iv = *(const int4*)(ii + e4);
            int4 jv = *(const int4*)(jj + e4);
            unsigned int vi = (unsigned)xv[iv.x] | ((unsigned)xv[iv.y] << 8) |
                              ((unsigned)xv[iv.z] << 16) | ((unsigned)xv[iv.w] << 24);
            unsigned int vj = (unsigned)xv[jv.x] | ((unsigned)xv[jv.y] << 8) |
                              ((unsigned)xv[jv.z] << 16) | ((unsigned)xv[jv.w] << 24);
            *(unsigned int*)(wsb + WSB_VI + e4) = vi;
            *(unsigned int*)(wsb + WSB_VJ + e4) = vj;
        }
    }
}

__device__ __forceinline__ float silu_f(float x) {
    return x / (1.f + __expf(-x));
}

// ---------------- main: all-register pb + table C-init + MFMA + silu ----------------
__global__ __launch_bounds__(1024, 4) void edge_kernel(
    const float* __restrict__ pair_basis,
    const char*  __restrict__ wsb,
    float* __restrict__ out)
{
    __shared__ __align__(16) _Float16 sTUW[WSU_TUW];   // T,U,W3 : 86528 B
    const _Float16* ws = (const _Float16*)wsb;
    const int tid = threadIdx.x;
    {   // stage T/U/W3 (contiguous in ws) into LDS
        const uint4* src = (const uint4*)ws;
        uint4* dst = (uint4*)sTUW;
        for (int c = tid; c < (WSU_TUW * 2 / 16); c += 1024) dst[c] = src[c];
    }
    const int lane = tid & 63;
    const int w    = tid >> 6;     // wave 0..15
    const int m    = lane & 15;
    const int g    = lane >> 4;

    // resident W_pair^T A-fragments
    f16x8 wpf[8];
    #pragma unroll
    for (int hf = 0; hf < 8; ++hf)
        wpf[hf] = *(const f16x8*)(ws + WSU_WP + (hf * 64 + lane) * 8);
    __syncthreads();

    const _Float16* sT  = sTUW;
    const _Float16* sU  = sTUW + WSU_U;
    const _Float16* sW3 = sTUW + WSU_W3;
    const unsigned char* viB = (const unsigned char*)(wsb + WSB_VI);
    const unsigned char* vjB = (const unsigned char*)(wsb + WSB_VJ);

    const int ntiles = (N_EDGES + 255) >> 8;   // 256 edges per block-tile (16/wave)
    for (int tile = blockIdx.x; tile < ntiles; tile += (int)gridDim.x) {
        const int e0 = tile * 256 + w * 16;
        if (e0 >= N_EDGES) continue;

        // ---- B2 frag: pair^T  (lane (m,g) supplies pair[e0+m][8g..8g+7]; k=16 row == 1 for bias)
        f16x8 b2 = {0, 0, 0, 0, 0, 0, 0, 0};
        if (g < 2) {
            const float* pr = pair_basis + (size_t)(e0 + m) * 16 + g * 8;
            f32x4 p0 = *(const f32x4*)pr;
            f32x4 p1 = *(const f32x4*)(pr + 4);
            b2[0] = (_Float16)p0[0]; b2[1] = (_Float16)p0[1];
            b2[2] = (_Float16)p0[2]; b2[3] = (_Float16)p0[3];
            b2[4] = (_Float16)p1[0]; b2[5] = (_Float16)p1[1];
            b2[6] = (_Float16)p1[2]; b2[7] = (_Float16)p1[3];
        } else if (g == 2) {
            b2[0] = (_Float16)1.0f;   // bias row k==16
        }

        // ---- swapped pair GEMM: D2[h][edge] -> silu -> pack straight into main-GEMM A-frags
        f16x8 a2[4];
        const f32x4 zero = {0.f, 0.f, 0.f, 0.f};
        #pragma unroll
        for (int ks = 0; ks < 4; ++ks) {
            f32x4 dA = __builtin_amdgcn_mfma_f32_16x16x32_f16(wpf[2 * ks],     b2, zero, 0, 0, 0);
            f32x4 dB = __builtin_amdgcn_mfma_f32_16x16x32_f16(wpf[2 * ks + 1], b2, zero, 0, 0, 0);
            f16x8 t2;
            #pragma unroll
            for (int r = 0; r < 4; ++r) {
                t2[r]     = (_Float16)silu_f(dA[r]);
                t2[4 + r] = (_Float16)silu_f(dB[r]);
            }
            a2[ks] = t2;
        }

        // ---- C init: T[vi] + U[vj] (b_emb already folded into T), vec8 reads
        unsigned int viq = *(const unsigned int*)(viB + e0 + 4 * g);
        unsigned int vjq = *(const unsigned int*)(vjB + e0 + 4 * g);
        f32x4 acc[8];
        #pragma unroll
        for (int r = 0; r < 4; ++r) {
            int vi = (viq >> (8 * r)) & 0xff;
            int vj = (vjq >> (8 * r)) & 0xff;
            f16x8 tv = *(const f16x8*)(sT + vi * HID + 8 * m);
            f16x8 uv = *(const f16x8*)(sU + vj * HID + 8 * m);
            #pragma unroll
            for (int nf = 0; nf < 8; ++nf)
                acc[nf][r] = (float)tv[nf] + (float)uv[nf];
        }

        // ---- main GEMM: acc += pb @ W3  (K-permuted B-frags from LDS)
        #pragma unroll
        for (int ks = 0; ks < 4; ++ks) {
            #pragma unroll
            for (int nf = 0; nf < 8; ++nf) {
                f16x8 bf = *(const f16x8*)(sW3 + ((ks * 8 + nf) * 64 + lane) * 8);
                acc[nf] = __builtin_amdgcn_mfma_f32_16x16x32_f16(a2[ks], bf, acc[nf], 0, 0, 0);
            }
        }

        // ---- epilogue: silu + contiguous float4 stores (cols 8m..8m+7 per thread)
        #pragma unroll
        for (int r = 0; r < 4; ++r) {
            float* op = out + (size_t)(e0 + 4 * g + r) * HID + 8 * m;
            f32x4 o0, o1;
            #pragma unroll
            for (int nf = 0; nf < 4; ++nf) {
                o0[nf] = silu_f(acc[nf][r]);
                o1[nf] = silu_f(acc[4 + nf][r]);
            }
            *(f32x4*)op       = o0;
            *(f32x4*)(op + 4) = o1;
        }
    }
}

extern "C" void kernel_launch(void* const* d_in, const int* in_sizes, int n_in,
                              void* d_out, int out_size, void* d_ws, size_t ws_size,
                              hipStream_t stream) {
    const int*   x          = (const int*)d_in[0];
    const float* pair_basis = (const float*)d_in[1];
    const int*   ii         = (const int*)d_in[2];
    const int*   jj         = (const int*)d_in[3];
    const float* emb_table  = (const float*)d_in[4];
    const float* W_pair     = (const float*)d_in[5];
    const float* b_pair     = (const float*)d_in[6];
    const float* W_emb      = (const float*)d_in[7];
    const float* b_emb      = (const float*)d_in[8];
    char* wsb = (char*)d_ws;
    float* out = (float*)d_out;

    const int ngather = (N_EDGES + 1023) / 1024;              // 977 blocks, 4 edges/thread
    prep_kernel<<<VOC + 64 + 16 + ngather, 256, 0, stream>>>(
        x, ii, jj, emb_table, W_pair, b_pair, W_emb, b_emb, wsb);
    edge_kernel<<<256, 1024, 0, stream>>>(pair_basis, wsb, out);
}